// Round 5
// baseline (2892.261 us; speedup 1.0000x reference)
//
#include <hip/hip_runtime.h>

#define NN 50000
#define NE 1600000
#define DIM 32
#define HS 0.1f
#define NBLK 1563      // cdiv(NN, 32)
#define GROUPS 391     // cdiv(NBLK, 4)
#define FCHUNK 16384
#define FCH 98         // cdiv(NE, FCHUNK)

static inline int cdiv(int a, int b) { return (a + b - 1) / b; }

typedef float vf2 __attribute__((ext_vector_type(2)));
typedef float vf4 __attribute__((ext_vector_type(4)));
typedef unsigned vu2 __attribute__((ext_vector_type(2)));

__device__ __forceinline__ float2 nt_load_f2(const float2* p) {
    vf2 v = __builtin_nontemporal_load((const vf2*)p);
    return make_float2(v.x, v.y);
}
__device__ __forceinline__ float4 nt_load_f4(const float* p) {
    vf4 v = __builtin_nontemporal_load((const vf4*)p);
    return make_float4(v.x, v.y, v.z, v.w);
}
__device__ __forceinline__ void nt_store_f4(float* p, float4 v) {
    vf4 t = {v.x, v.y, v.z, v.w};
    __builtin_nontemporal_store(t, (vf4*)p);
}
__device__ __forceinline__ void nt_store_u2(uint2* p, uint2 v) {
    vu2 t = {v.x, v.y};
    __builtin_nontemporal_store(t, (vu2*)p);
}

// bf16x4 (uint2) -> float4
__device__ __forceinline__ float4 bf4_to_f4(uint2 u) {
    float4 v;
    v.x = __uint_as_float(u.x << 16);
    v.y = __uint_as_float(u.x & 0xffff0000u);
    v.z = __uint_as_float(u.y << 16);
    v.w = __uint_as_float(u.y & 0xffff0000u);
    return v;
}
// pack 2 floats -> bf16x2 round-to-nearest-even
__device__ __forceinline__ unsigned pack_bf2(float a, float b) {
    unsigned ua = __float_as_uint(a);
    ua = (ua + 0x7fffu + ((ua >> 16) & 1u)) >> 16;
    unsigned ub = __float_as_uint(b);
    ub = (ub + 0x7fffu + ((ub >> 16) & 1u)) & 0xffff0000u;
    return ua | ub;
}

// ---------------- setup kernels ----------------

__global__ void k_zero_ints(int* __restrict__ p, int n) {
    int i = blockIdx.x * blockDim.x + threadIdx.x;
    if (i < n) p[i] = 0;
}

__global__ void k_hist(const int* __restrict__ dst, int* __restrict__ cnt) {
    int i = blockIdx.x * blockDim.x + threadIdx.x;
    if (i < NE) atomicAdd(&cnt[dst[i]], 1);
}

__global__ __launch_bounds__(1024) void k_scanA(const int* __restrict__ cnt,
                                                int* __restrict__ row_ptr,
                                                int* __restrict__ partials) {
    __shared__ int s[1024];
    int t = threadIdx.x;
    int g = blockIdx.x * 1024 + t;
    int v = (g < NN) ? cnt[g] : 0;
    s[t] = v;
    __syncthreads();
    for (int off = 1; off < 1024; off <<= 1) {
        int add = (t >= off) ? s[t - off] : 0;
        __syncthreads();
        s[t] += add;
        __syncthreads();
    }
    if (g < NN) row_ptr[g + 1] = s[t];
    if (t == 1023) partials[blockIdx.x] = s[t];
}

__global__ void k_scanB(int* __restrict__ partials, int nb) {
    if (threadIdx.x == 0 && blockIdx.x == 0) {
        int run = 0;
        for (int i = 0; i < nb; i++) { int v = partials[i]; partials[i] = run; run += v; }
    }
}

__global__ void k_scanC(int* __restrict__ row_ptr, const int* __restrict__ partials) {
    int g = blockIdx.x * blockDim.x + threadIdx.x;
    if (g < NN) row_ptr[g + 1] += partials[g >> 10];
    if (g == 0) row_ptr[0] = 0;
}

__global__ void k_dis(const int* __restrict__ row_ptr, float* __restrict__ dis) {
    int n = blockIdx.x * blockDim.x + threadIdx.x;
    if (n < NN) {
        int deg = row_ptr[n + 1] - row_ptr[n];
        dis[n] = rsqrtf((float)deg + 1.0f);  // +1 self-loop
    }
}

// sliced CSR fill: block handles dst-slice v = blockIdx%8 over chunk blockIdx/8.
// All cw writes of a slice stay within one 1.6MB region -> L2 write-combining
// (under blockIdx%8 ~ XCD round-robin; correctness independent of mapping).
__global__ __launch_bounds__(256) void k_fill(const int* __restrict__ src,
                                              const int* __restrict__ dst,
                                              const int* __restrict__ row_ptr,
                                              const float* __restrict__ dis,
                                              int* __restrict__ fill,
                                              float2* __restrict__ cw) {
    int v = blockIdx.x & 7;
    int c = blockIdx.x >> 3;
    int lo = v * (NN / 8), hi = lo + (NN / 8);
    int base = c * FCHUNK;
    int end = base + FCHUNK; if (end > NE) end = NE;
    for (int i = base + threadIdx.x; i < end; i += 256) {
        int d = dst[i];
        if (d >= lo && d < hi) {
            int s = src[i];
            int slot = row_ptr[d] + atomicAdd(&fill[d], 1);
            cw[slot] = make_float2(__int_as_float(s), dis[s] * dis[d]);
        }
    }
}

// ---------------- initial matmul (x @ W -> xw bf16, copy x -> x_cur) ----------------

__global__ __launch_bounds__(256) void k_matmul(const float* __restrict__ src,
                                                const float* __restrict__ W,
                                                uint2* __restrict__ xw,
                                                float* __restrict__ copy_out) {
    __shared__ float sW[DIM * DIM];
    __shared__ float sX[32 * 33];
    int t = threadIdx.x;
#pragma unroll
    for (int k = 0; k < 4; k++) { int i = k * 256 + t; sW[i] = W[i]; }
    size_t base = (size_t)blockIdx.x * 32 * DIM;
#pragma unroll
    for (int k = 0; k < 4; k++) {
        int i = k * 256 + t;
        size_t g = base + i;
        float v = 0.f;
        if (g < (size_t)NN * DIM) {
            v = src[g];
            copy_out[g] = v;
        }
        sX[(i >> 5) * 33 + (i & 31)] = v;
    }
    __syncthreads();
    int r = t >> 3, oct = t & 7;
    int row = blockIdx.x * 32 + r;
    if (row >= NN) return;
    float a0 = 0.f, a1 = 0.f, a2 = 0.f, a3 = 0.f;
    const float* xr = &sX[r * 33];
#pragma unroll
    for (int i = 0; i < DIM; i++) {
        float xv = xr[i];
        const float* wr = &sW[i * DIM + oct * 4];
        a0 = fmaf(xv, wr[0], a0);
        a1 = fmaf(xv, wr[1], a1);
        a2 = fmaf(xv, wr[2], a2);
        a3 = fmaf(xv, wr[3], a3);
    }
    xw[(size_t)row * 8 + oct] = make_uint2(pack_bf2(a0, a1), pack_bf2(a2, a3));
}

// ---------------- fused stage kernel ----------------
// Sign chosen by blockIdx%8 (<4 -> pos, >=4 -> neg): each XCD's L2 holds only
// one sign's 3.2MB xw. Streams (cw/x_cur/acc/stores) are non-temporal.

struct SignP {
    const int* row_ptr; const float2* cw; const float* dis;
    const uint2* xw_in; uint2* xw_out;
    float* acc; float* x_cur;
    const float* W; const float* b; const float* wt;
    float* zout;
};
struct StageArgs { SignP s[2]; float t, acc_coef, stage_coef; int mode; };

#define EDGE_FMA(p, u)                                              \
    {                                                               \
        float4 v = bf4_to_f4(u);                                    \
        sum.x = fmaf((p).y, v.x, sum.x);                            \
        sum.y = fmaf((p).y, v.y, sum.y);                            \
        sum.z = fmaf((p).y, v.z, sum.z);                            \
        sum.w = fmaf((p).y, v.w, sum.w);                            \
    }

__global__ __launch_bounds__(256) void k_stage(StageArgs A) {
    int r8 = blockIdx.x & 7;
    int g8 = blockIdx.x >> 3;
    int sg = r8 >> 2;
    int blk = g8 * 4 + (r8 & 3);
    if (blk >= NBLK) return;   // uniform across block
    SignP P = A.s[sg];

    __shared__ float sW[DIM * DIM];   // 4 KB
    __shared__ float sR[32 * 36];     // stride 36: 16B-aligned, conflict-free
    int tid = threadIdx.x;
    if (A.mode != 5) {
#pragma unroll
        for (int k = 0; k < 4; k++) { int i = k * 256 + tid; sW[i] = P.W[i]; }
    }

    int q = tid & 7;              // column quad (4 cols = 8 B bf16)
    int nl = tid >> 3;            // local node 0..31
    int n = blk * 32 + nl;
    bool active = n < NN;
    float4 r4 = make_float4(0.f, 0.f, 0.f, 0.f);

    if (active) {
        int e0 = P.row_ptr[n], e1 = P.row_ptr[n + 1];
        const uint2* xwq = P.xw_in + q;   // row stride = 8 uint2 (64 B)
        float4 sum = make_float4(0.f, 0.f, 0.f, 0.f);
        int e = e0;
        for (; e + 7 < e1; e += 8) {
            float2 p0 = nt_load_f2(&P.cw[e]);
            float2 p1 = nt_load_f2(&P.cw[e + 1]);
            float2 p2 = nt_load_f2(&P.cw[e + 2]);
            float2 p3 = nt_load_f2(&P.cw[e + 3]);
            float2 p4 = nt_load_f2(&P.cw[e + 4]);
            float2 p5 = nt_load_f2(&P.cw[e + 5]);
            float2 p6 = nt_load_f2(&P.cw[e + 6]);
            float2 p7 = nt_load_f2(&P.cw[e + 7]);
            uint2 u0 = xwq[(size_t)__float_as_int(p0.x) * 8];
            uint2 u1 = xwq[(size_t)__float_as_int(p1.x) * 8];
            uint2 u2 = xwq[(size_t)__float_as_int(p2.x) * 8];
            uint2 u3 = xwq[(size_t)__float_as_int(p3.x) * 8];
            uint2 u4 = xwq[(size_t)__float_as_int(p4.x) * 8];
            uint2 u5 = xwq[(size_t)__float_as_int(p5.x) * 8];
            uint2 u6 = xwq[(size_t)__float_as_int(p6.x) * 8];
            uint2 u7 = xwq[(size_t)__float_as_int(p7.x) * 8];
            EDGE_FMA(p0, u0) EDGE_FMA(p1, u1) EDGE_FMA(p2, u2) EDGE_FMA(p3, u3)
            EDGE_FMA(p4, u4) EDGE_FMA(p5, u5) EDGE_FMA(p6, u6) EDGE_FMA(p7, u7)
        }
        for (; e < e1; ++e) {
            float2 p = nt_load_f2(&P.cw[e]);
            uint2 u = xwq[(size_t)__float_as_int(p.x) * 8];
            EDGE_FMA(p, u)
        }
        float dn = P.dis[n];
        float sn = dn * dn;
        float4 vn = bf4_to_f4(xwq[(size_t)n * 8]);
        float4 bb = *(const float4*)&P.b[q * 4];
        sum.x = fmaf(sn, vn.x, sum.x) + bb.x;
        sum.y = fmaf(sn, vn.y, sum.y) + bb.y;
        sum.z = fmaf(sn, vn.z, sum.z) + bb.z;
        sum.w = fmaf(sn, vn.w, sum.w) + bb.w;
        float4 w4 = *(const float4*)&P.wt[q * 4];
        float t = A.t;
        float4 kv;
        kv.x = fmaxf(sum.x, 0.f) / (1.f + __expf(-t * w4.x));
        kv.y = fmaxf(sum.y, 0.f) / (1.f + __expf(-t * w4.y));
        kv.z = fmaxf(sum.z, 0.f) / (1.f + __expf(-t * w4.z));
        kv.w = fmaxf(sum.w, 0.f) / (1.f + __expf(-t * w4.w));

        size_t o = (size_t)n * DIM + q * 4;
        float4 xc = nt_load_f4(&P.x_cur[o]);
        if (A.mode == 1) {
            nt_store_f4(&P.acc[o], kv);
            r4.x = fmaf(A.stage_coef, kv.x, xc.x); r4.y = fmaf(A.stage_coef, kv.y, xc.y);
            r4.z = fmaf(A.stage_coef, kv.z, xc.z); r4.w = fmaf(A.stage_coef, kv.w, xc.w);
        } else if (A.mode <= 3) {
            float4 ap = nt_load_f4(&P.acc[o]);
            float4 a;
            a.x = fmaf(A.acc_coef, kv.x, ap.x); a.y = fmaf(A.acc_coef, kv.y, ap.y);
            a.z = fmaf(A.acc_coef, kv.z, ap.z); a.w = fmaf(A.acc_coef, kv.w, ap.w);
            nt_store_f4(&P.acc[o], a);
            r4.x = fmaf(A.stage_coef, kv.x, xc.x); r4.y = fmaf(A.stage_coef, kv.y, xc.y);
            r4.z = fmaf(A.stage_coef, kv.z, xc.z); r4.w = fmaf(A.stage_coef, kv.w, xc.w);
        } else {
            float4 ap = nt_load_f4(&P.acc[o]);
            float4 a;
            a.x = ap.x + kv.x; a.y = ap.y + kv.y;
            a.z = ap.z + kv.z; a.w = ap.w + kv.w;
            r4.x = fmaf(HS / 6.f, a.x, xc.x); r4.y = fmaf(HS / 6.f, a.y, xc.y);
            r4.z = fmaf(HS / 6.f, a.z, xc.z); r4.w = fmaf(HS / 6.f, a.w, xc.w);
            if (A.mode == 4) {
                nt_store_f4(&P.x_cur[o], r4);
            } else {
                nt_store_f4(&P.zout[o], r4);
            }
        }
    }

    if (A.mode == 5) return;  // uniform; no thread of this block hits the barrier

    // epilogue matmul: xw_out[n] = r4-row @ W, stored bf16 (non-temporal)
    *(float4*)&sR[nl * 36 + q * 4] = r4;
    __syncthreads();
    if (active) {
        float4 y = make_float4(0.f, 0.f, 0.f, 0.f);
        const float* row = &sR[nl * 36];
#pragma unroll
        for (int i = 0; i < DIM; i++) {
            float sv = row[i];
            float4 w = *(const float4*)&sW[i * DIM + q * 4];
            y.x = fmaf(sv, w.x, y.x); y.y = fmaf(sv, w.y, y.y);
            y.z = fmaf(sv, w.z, y.z); y.w = fmaf(sv, w.w, y.w);
        }
        nt_store_u2(&P.xw_out[(size_t)n * 8 + q],
                    make_uint2(pack_bf2(y.x, y.y), pack_bf2(y.z, y.w)));
    }
}

// ---------------- host ----------------

extern "C" void kernel_launch(void* const* d_in, const int* in_sizes, int n_in,
                              void* d_out, int out_size, void* d_ws, size_t ws_size,
                              hipStream_t stream) {
    const float* x   = (const float*)d_in[0];
    const int* epos  = (const int*)d_in[1];
    const int* eneg  = (const int*)d_in[2];
    const float* Wp  = (const float*)d_in[3];
    const float* bp  = (const float*)d_in[4];
    const float* wtp = (const float*)d_in[5];
    const float* Wn  = (const float*)d_in[6];
    const float* bn  = (const float*)d_in[7];
    const float* wtn = (const float*)d_in[8];
    float* out = (float*)d_out;

    char* ws = (char*)d_ws;
    size_t off = 0;
    auto alloc = [&](size_t bytes) -> void* {
        void* p = ws + off;
        off += (bytes + 255) & ~(size_t)255;
        return p;
    };

    struct Sign {
        int *row_ptr, *cnt, *fill, *partials;
        float* dis;
        float2* cw;
        float *x_cur, *acc;
        uint2* xwbuf[2];
        const int *src, *dst;
        const float *W, *b, *wt;
        float* zout;
    } S[2];

    for (int s = 0; s < 2; s++) {
        S[s].row_ptr  = (int*)alloc((NN + 1) * sizeof(int));
        int* cntfill  = (int*)alloc((size_t)2 * NN * sizeof(int));
        S[s].cnt = cntfill;
        S[s].fill = cntfill + NN;
        S[s].partials = (int*)alloc(256);
        S[s].dis      = (float*)alloc(NN * sizeof(float));
        S[s].cw       = (float2*)alloc((size_t)NE * sizeof(float2));
        S[s].x_cur    = (float*)alloc((size_t)NN * DIM * sizeof(float));
        S[s].acc      = (float*)alloc((size_t)NN * DIM * sizeof(float));
        S[s].xwbuf[0] = (uint2*)alloc((size_t)NN * DIM * 2);
        S[s].xwbuf[1] = (uint2*)alloc((size_t)NN * DIM * 2);
    }
    S[0].src = epos; S[0].dst = epos + NE; S[0].W = Wp; S[0].b = bp; S[0].wt = wtp;
    S[0].zout = out;
    S[1].src = eneg; S[1].dst = eneg + NE; S[1].W = Wn; S[1].b = bn; S[1].wt = wtn;
    S[1].zout = out + (size_t)NN * DIM;

    const int nbScan = cdiv(NN, 1024);

    // ---- setup: build CSR + norms for both signs ----
    for (int s = 0; s < 2; s++) {
        k_zero_ints<<<cdiv(2 * NN, 256), 256, 0, stream>>>(S[s].cnt, 2 * NN);
        k_hist<<<cdiv(NE, 256), 256, 0, stream>>>(S[s].dst, S[s].cnt);
        k_scanA<<<nbScan, 1024, 0, stream>>>(S[s].cnt, S[s].row_ptr, S[s].partials);
        k_scanB<<<1, 1, 0, stream>>>(S[s].partials, nbScan);
        k_scanC<<<cdiv(NN, 256), 256, 0, stream>>>(S[s].row_ptr, S[s].partials);
        k_dis<<<cdiv(NN, 256), 256, 0, stream>>>(S[s].row_ptr, S[s].dis);
        k_fill<<<FCH * 8, 256, 0, stream>>>(S[s].src, S[s].dst, S[s].row_ptr,
                                            S[s].dis, S[s].fill, S[s].cw);
    }

    // initial xw = bf16(x @ W), x_cur = x
    for (int s = 0; s < 2; s++)
        k_matmul<<<NBLK, 256, 0, stream>>>(x, S[s].W, S[s].xwbuf[0], S[s].x_cur);

    // ---- RK4 main loop: 4 fused stages per step, both signs per dispatch ----
    for (int st = 0; st < 10; st++) {
        float tb = HS * (float)st;
        struct Ph { float t, ac, sc; int mode, in, out; } ph[4] = {
            { tb,             1.f, HS * 0.5f, 1,              0, 1 },
            { tb + HS * 0.5f, 2.f, HS * 0.5f, 2,              1, 0 },
            { tb + HS * 0.5f, 2.f, HS,        3,              0, 1 },
            { tb + HS,        1.f, 0.f,       st == 9 ? 5 : 4, 1, 0 },
        };
        for (int p = 0; p < 4; p++) {
            StageArgs A;
            for (int s = 0; s < 2; s++) {
                A.s[s].row_ptr = S[s].row_ptr;
                A.s[s].cw      = S[s].cw;
                A.s[s].dis     = S[s].dis;
                A.s[s].xw_in   = S[s].xwbuf[ph[p].in];
                A.s[s].xw_out  = S[s].xwbuf[ph[p].out];
                A.s[s].acc     = S[s].acc;
                A.s[s].x_cur   = S[s].x_cur;
                A.s[s].W       = S[s].W;
                A.s[s].b       = S[s].b;
                A.s[s].wt      = S[s].wt;
                A.s[s].zout    = S[s].zout;
            }
            A.t = ph[p].t; A.acc_coef = ph[p].ac; A.stage_coef = ph[p].sc;
            A.mode = ph[p].mode;
            k_stage<<<GROUPS * 8, 256, 0, stream>>>(A);
        }
    }
}

// Round 6
// 1863.390 us; speedup vs baseline: 1.5522x; 1.5522x over previous
//
#include <hip/hip_runtime.h>

#define NN 50000
#define NE 1600000
#define DIM 32
#define HS 0.1f
#define NBLK 1563      // cdiv(NN, 32)
#define GROUPS 391     // cdiv(NBLK, 4)

static inline int cdiv(int a, int b) { return (a + b - 1) / b; }

// bf16x4 (uint2) -> float4
__device__ __forceinline__ float4 bf4_to_f4(uint2 u) {
    float4 v;
    v.x = __uint_as_float(u.x << 16);
    v.y = __uint_as_float(u.x & 0xffff0000u);
    v.z = __uint_as_float(u.y << 16);
    v.w = __uint_as_float(u.y & 0xffff0000u);
    return v;
}
// pack 2 floats -> bf16x2 round-to-nearest-even
__device__ __forceinline__ unsigned pack_bf2(float a, float b) {
    unsigned ua = __float_as_uint(a);
    ua = (ua + 0x7fffu + ((ua >> 16) & 1u)) >> 16;
    unsigned ub = __float_as_uint(b);
    ub = (ub + 0x7fffu + ((ub >> 16) & 1u)) & 0xffff0000u;
    return ua | ub;
}

// ---------------- setup kernels ----------------

__global__ void k_zero_ints(int* __restrict__ p, int n) {
    int i = blockIdx.x * blockDim.x + threadIdx.x;
    if (i < n) p[i] = 0;
}

__global__ void k_hist(const int* __restrict__ dst, int* __restrict__ cnt) {
    int i = blockIdx.x * blockDim.x + threadIdx.x;
    if (i < NE) atomicAdd(&cnt[dst[i]], 1);
}

__global__ __launch_bounds__(1024) void k_scanA(const int* __restrict__ cnt,
                                                int* __restrict__ row_ptr,
                                                int* __restrict__ partials) {
    __shared__ int s[1024];
    int t = threadIdx.x;
    int g = blockIdx.x * 1024 + t;
    int v = (g < NN) ? cnt[g] : 0;
    s[t] = v;
    __syncthreads();
    for (int off = 1; off < 1024; off <<= 1) {
        int add = (t >= off) ? s[t - off] : 0;
        __syncthreads();
        s[t] += add;
        __syncthreads();
    }
    if (g < NN) row_ptr[g + 1] = s[t];
    if (t == 1023) partials[blockIdx.x] = s[t];
}

__global__ void k_scanB(int* __restrict__ partials, int nb) {
    if (threadIdx.x == 0 && blockIdx.x == 0) {
        int run = 0;
        for (int i = 0; i < nb; i++) { int v = partials[i]; partials[i] = run; run += v; }
    }
}

__global__ void k_scanC(int* __restrict__ row_ptr, const int* __restrict__ partials) {
    int g = blockIdx.x * blockDim.x + threadIdx.x;
    if (g < NN) row_ptr[g + 1] += partials[g >> 10];
    if (g == 0) row_ptr[0] = 0;
}

__global__ void k_dis(const int* __restrict__ row_ptr, float* __restrict__ dis) {
    int n = blockIdx.x * blockDim.x + threadIdx.x;
    if (n < NN) {
        int deg = row_ptr[n + 1] - row_ptr[n];
        dis[n] = rsqrtf((float)deg + 1.0f);  // +1 self-loop
    }
}

// scatter edges into CSR slots; 4B record = (src << 15) | fix15(dis[s]*dis[d])
__global__ void k_fill(const int* __restrict__ src, const int* __restrict__ dst,
                       const int* __restrict__ row_ptr, const float* __restrict__ dis,
                       int* __restrict__ fill, unsigned* __restrict__ cw) {
    int i = blockIdx.x * blockDim.x + threadIdx.x;
    if (i < NE) {
        int s = src[i], d = dst[i];
        int slot = row_ptr[d] + atomicAdd(&fill[d], 1);
        float w = dis[s] * dis[d];   // in (0, 1]
        cw[slot] = ((unsigned)s << 15) | (unsigned)(w * 32767.f + 0.5f);
    }
}

// ---------------- initial matmul (x @ W -> xw bf16, copy x -> x_cur) ----------------

__global__ __launch_bounds__(256) void k_matmul(const float* __restrict__ src,
                                                const float* __restrict__ W,
                                                uint2* __restrict__ xw,
                                                float* __restrict__ copy_out) {
    __shared__ float sW[DIM * DIM];
    __shared__ float sX[32 * 33];
    int t = threadIdx.x;
#pragma unroll
    for (int k = 0; k < 4; k++) { int i = k * 256 + t; sW[i] = W[i]; }
    size_t base = (size_t)blockIdx.x * 32 * DIM;
#pragma unroll
    for (int k = 0; k < 4; k++) {
        int i = k * 256 + t;
        size_t g = base + i;
        float v = 0.f;
        if (g < (size_t)NN * DIM) {
            v = src[g];
            copy_out[g] = v;
        }
        sX[(i >> 5) * 33 + (i & 31)] = v;
    }
    __syncthreads();
    int r = t >> 3, oct = t & 7;
    int row = blockIdx.x * 32 + r;
    if (row >= NN) return;
    float a0 = 0.f, a1 = 0.f, a2 = 0.f, a3 = 0.f;
    const float* xr = &sX[r * 33];
#pragma unroll
    for (int i = 0; i < DIM; i++) {
        float xv = xr[i];
        const float* wr = &sW[i * DIM + oct * 4];
        a0 = fmaf(xv, wr[0], a0);
        a1 = fmaf(xv, wr[1], a1);
        a2 = fmaf(xv, wr[2], a2);
        a3 = fmaf(xv, wr[3], a3);
    }
    xw[(size_t)row * 8 + oct] = make_uint2(pack_bf2(a0, a1), pack_bf2(a2, a3));
}

// ---------------- fused stage kernel ----------------
// Sign chosen by blockIdx%8 (<4 -> pos, >=4 -> neg): under round-robin
// block->XCD dispatch each XCD's L2 sees only one sign's 3.2MB xw.
// NO non-temporal hints anywhere (R5 lesson: cw has 16-records/line reuse).

struct SignP {
    const int* row_ptr; const unsigned* cw; const float* dis;
    const uint2* xw_in; uint2* xw_out;
    float* acc; float* x_cur;
    const float* W; const float* b; const float* wt;
    float* zout;
};
struct StageArgs { SignP s[2]; float t, acc_coef, stage_coef; int mode; };

#define EDGE_FMA(r, u)                                              \
    {                                                               \
        float wE = (float)((r) & 32767u) * (1.f / 32767.f);         \
        float4 v = bf4_to_f4(u);                                    \
        sum.x = fmaf(wE, v.x, sum.x);                               \
        sum.y = fmaf(wE, v.y, sum.y);                               \
        sum.z = fmaf(wE, v.z, sum.z);                               \
        sum.w = fmaf(wE, v.w, sum.w);                               \
    }

__global__ __launch_bounds__(256) void k_stage(StageArgs A) {
    int r8 = blockIdx.x & 7;
    int g8 = blockIdx.x >> 3;
    int sg = r8 >> 2;
    int blk = g8 * 4 + (r8 & 3);
    if (blk >= NBLK) return;   // uniform across block
    SignP P = A.s[sg];

    __shared__ float sW[DIM * DIM];   // 4 KB
    __shared__ float sR[32 * 36];     // stride 36: 16B-aligned, conflict-free
    int tid = threadIdx.x;
    if (A.mode != 5) {
#pragma unroll
        for (int k = 0; k < 4; k++) { int i = k * 256 + tid; sW[i] = P.W[i]; }
    }

    int q = tid & 7;              // column quad (4 cols = 8 B bf16)
    int nl = tid >> 3;            // local node 0..31
    int n = blk * 32 + nl;
    bool active = n < NN;
    float4 r4 = make_float4(0.f, 0.f, 0.f, 0.f);

    if (active) {
        int e0 = P.row_ptr[n], e1 = P.row_ptr[n + 1];
        const uint2* xwq = P.xw_in + q;   // row stride = 8 uint2 (64 B)
        float4 sum = make_float4(0.f, 0.f, 0.f, 0.f);
        int e = e0;
        // unroll 8: 8 rec loads + 8 independent 8B gathers in flight
        for (; e + 7 < e1; e += 8) {
            unsigned r0 = P.cw[e];
            unsigned r1 = P.cw[e + 1];
            unsigned r2 = P.cw[e + 2];
            unsigned r3 = P.cw[e + 3];
            unsigned r4_ = P.cw[e + 4];
            unsigned r5 = P.cw[e + 5];
            unsigned r6 = P.cw[e + 6];
            unsigned r7 = P.cw[e + 7];
            uint2 u0 = xwq[(size_t)(r0 >> 15) * 8];
            uint2 u1 = xwq[(size_t)(r1 >> 15) * 8];
            uint2 u2 = xwq[(size_t)(r2 >> 15) * 8];
            uint2 u3 = xwq[(size_t)(r3 >> 15) * 8];
            uint2 u4 = xwq[(size_t)(r4_ >> 15) * 8];
            uint2 u5 = xwq[(size_t)(r5 >> 15) * 8];
            uint2 u6 = xwq[(size_t)(r6 >> 15) * 8];
            uint2 u7 = xwq[(size_t)(r7 >> 15) * 8];
            EDGE_FMA(r0, u0) EDGE_FMA(r1, u1) EDGE_FMA(r2, u2) EDGE_FMA(r3, u3)
            EDGE_FMA(r4_, u4) EDGE_FMA(r5, u5) EDGE_FMA(r6, u6) EDGE_FMA(r7, u7)
        }
        for (; e < e1; ++e) {
            unsigned r = P.cw[e];
            uint2 u = xwq[(size_t)(r >> 15) * 8];
            EDGE_FMA(r, u)
        }
        float dn = P.dis[n];
        float sn = dn * dn;
        float4 vn = bf4_to_f4(xwq[(size_t)n * 8]);
        float4 bb = *(const float4*)&P.b[q * 4];
        sum.x = fmaf(sn, vn.x, sum.x) + bb.x;
        sum.y = fmaf(sn, vn.y, sum.y) + bb.y;
        sum.z = fmaf(sn, vn.z, sum.z) + bb.z;
        sum.w = fmaf(sn, vn.w, sum.w) + bb.w;
        float4 w4 = *(const float4*)&P.wt[q * 4];
        float t = A.t;
        float4 kv;
        kv.x = fmaxf(sum.x, 0.f) / (1.f + __expf(-t * w4.x));
        kv.y = fmaxf(sum.y, 0.f) / (1.f + __expf(-t * w4.y));
        kv.z = fmaxf(sum.z, 0.f) / (1.f + __expf(-t * w4.z));
        kv.w = fmaxf(sum.w, 0.f) / (1.f + __expf(-t * w4.w));

        size_t o = (size_t)n * DIM + q * 4;
        float4 xc = *(const float4*)&P.x_cur[o];
        if (A.mode == 1) {
            *(float4*)&P.acc[o] = kv;
            r4.x = fmaf(A.stage_coef, kv.x, xc.x); r4.y = fmaf(A.stage_coef, kv.y, xc.y);
            r4.z = fmaf(A.stage_coef, kv.z, xc.z); r4.w = fmaf(A.stage_coef, kv.w, xc.w);
        } else if (A.mode <= 3) {
            float4 ap = *(const float4*)&P.acc[o];
            float4 a;
            a.x = fmaf(A.acc_coef, kv.x, ap.x); a.y = fmaf(A.acc_coef, kv.y, ap.y);
            a.z = fmaf(A.acc_coef, kv.z, ap.z); a.w = fmaf(A.acc_coef, kv.w, ap.w);
            *(float4*)&P.acc[o] = a;
            r4.x = fmaf(A.stage_coef, kv.x, xc.x); r4.y = fmaf(A.stage_coef, kv.y, xc.y);
            r4.z = fmaf(A.stage_coef, kv.z, xc.z); r4.w = fmaf(A.stage_coef, kv.w, xc.w);
        } else {
            float4 ap = *(const float4*)&P.acc[o];
            float4 a;
            a.x = ap.x + kv.x; a.y = ap.y + kv.y;
            a.z = ap.z + kv.z; a.w = ap.w + kv.w;
            r4.x = fmaf(HS / 6.f, a.x, xc.x); r4.y = fmaf(HS / 6.f, a.y, xc.y);
            r4.z = fmaf(HS / 6.f, a.z, xc.z); r4.w = fmaf(HS / 6.f, a.w, xc.w);
            if (A.mode == 4) {
                *(float4*)&P.x_cur[o] = r4;
            } else {
                *(float4*)&P.zout[o] = r4;
            }
        }
    }

    if (A.mode == 5) return;  // uniform; no thread of this block hits the barrier

    // epilogue matmul: xw_out[n] = r4-row @ W, stored bf16
    *(float4*)&sR[nl * 36 + q * 4] = r4;
    __syncthreads();
    if (active) {
        float4 y = make_float4(0.f, 0.f, 0.f, 0.f);
        const float* row = &sR[nl * 36];
#pragma unroll
        for (int i = 0; i < DIM; i++) {
            float sv = row[i];
            float4 w = *(const float4*)&sW[i * DIM + q * 4];
            y.x = fmaf(sv, w.x, y.x); y.y = fmaf(sv, w.y, y.y);
            y.z = fmaf(sv, w.z, y.z); y.w = fmaf(sv, w.w, y.w);
        }
        P.xw_out[(size_t)n * 8 + q] = make_uint2(pack_bf2(y.x, y.y), pack_bf2(y.z, y.w));
    }
}

// ---------------- host ----------------

extern "C" void kernel_launch(void* const* d_in, const int* in_sizes, int n_in,
                              void* d_out, int out_size, void* d_ws, size_t ws_size,
                              hipStream_t stream) {
    const float* x   = (const float*)d_in[0];
    const int* epos  = (const int*)d_in[1];
    const int* eneg  = (const int*)d_in[2];
    const float* Wp  = (const float*)d_in[3];
    const float* bp  = (const float*)d_in[4];
    const float* wtp = (const float*)d_in[5];
    const float* Wn  = (const float*)d_in[6];
    const float* bn  = (const float*)d_in[7];
    const float* wtn = (const float*)d_in[8];
    float* out = (float*)d_out;

    char* ws = (char*)d_ws;
    size_t off = 0;
    auto alloc = [&](size_t bytes) -> void* {
        void* p = ws + off;
        off += (bytes + 255) & ~(size_t)255;
        return p;
    };

    struct Sign {
        int *row_ptr, *cnt, *fill, *partials;
        float* dis;
        unsigned* cw;
        float *x_cur, *acc;
        uint2* xwbuf[2];
        const int *src, *dst;
        const float *W, *b, *wt;
        float* zout;
    } S[2];

    for (int s = 0; s < 2; s++) {
        S[s].row_ptr  = (int*)alloc((NN + 1) * sizeof(int));
        int* cntfill  = (int*)alloc((size_t)2 * NN * sizeof(int));
        S[s].cnt = cntfill;
        S[s].fill = cntfill + NN;
        S[s].partials = (int*)alloc(256);
        S[s].dis      = (float*)alloc(NN * sizeof(float));
        S[s].cw       = (unsigned*)alloc((size_t)NE * sizeof(unsigned));
        S[s].x_cur    = (float*)alloc((size_t)NN * DIM * sizeof(float));
        S[s].acc      = (float*)alloc((size_t)NN * DIM * sizeof(float));
        S[s].xwbuf[0] = (uint2*)alloc((size_t)NN * DIM * 2);
        S[s].xwbuf[1] = (uint2*)alloc((size_t)NN * DIM * 2);
    }
    S[0].src = epos; S[0].dst = epos + NE; S[0].W = Wp; S[0].b = bp; S[0].wt = wtp;
    S[0].zout = out;
    S[1].src = eneg; S[1].dst = eneg + NE; S[1].W = Wn; S[1].b = bn; S[1].wt = wtn;
    S[1].zout = out + (size_t)NN * DIM;

    const int nbScan = cdiv(NN, 1024);

    // ---- setup: build CSR + norms for both signs ----
    for (int s = 0; s < 2; s++) {
        k_zero_ints<<<cdiv(2 * NN, 256), 256, 0, stream>>>(S[s].cnt, 2 * NN);
        k_hist<<<cdiv(NE, 256), 256, 0, stream>>>(S[s].dst, S[s].cnt);
        k_scanA<<<nbScan, 1024, 0, stream>>>(S[s].cnt, S[s].row_ptr, S[s].partials);
        k_scanB<<<1, 1, 0, stream>>>(S[s].partials, nbScan);
        k_scanC<<<cdiv(NN, 256), 256, 0, stream>>>(S[s].row_ptr, S[s].partials);
        k_dis<<<cdiv(NN, 256), 256, 0, stream>>>(S[s].row_ptr, S[s].dis);
        k_fill<<<cdiv(NE, 256), 256, 0, stream>>>(S[s].src, S[s].dst, S[s].row_ptr,
                                                  S[s].dis, S[s].fill, S[s].cw);
    }

    // initial xw = bf16(x @ W), x_cur = x
    for (int s = 0; s < 2; s++)
        k_matmul<<<NBLK, 256, 0, stream>>>(x, S[s].W, S[s].xwbuf[0], S[s].x_cur);

    // ---- RK4 main loop: 4 fused stages per step, both signs per dispatch ----
    for (int st = 0; st < 10; st++) {
        float tb = HS * (float)st;
        struct Ph { float t, ac, sc; int mode, in, out; } ph[4] = {
            { tb,             1.f, HS * 0.5f, 1,              0, 1 },
            { tb + HS * 0.5f, 2.f, HS * 0.5f, 2,              1, 0 },
            { tb + HS * 0.5f, 2.f, HS,        3,              0, 1 },
            { tb + HS,        1.f, 0.f,       st == 9 ? 5 : 4, 1, 0 },
        };
        for (int p = 0; p < 4; p++) {
            StageArgs A;
            for (int s = 0; s < 2; s++) {
                A.s[s].row_ptr = S[s].row_ptr;
                A.s[s].cw      = S[s].cw;
                A.s[s].dis     = S[s].dis;
                A.s[s].xw_in   = S[s].xwbuf[ph[p].in];
                A.s[s].xw_out  = S[s].xwbuf[ph[p].out];
                A.s[s].acc     = S[s].acc;
                A.s[s].x_cur   = S[s].x_cur;
                A.s[s].W       = S[s].W;
                A.s[s].b       = S[s].b;
                A.s[s].wt      = S[s].wt;
                A.s[s].zout    = S[s].zout;
            }
            A.t = ph[p].t; A.acc_coef = ph[p].ac; A.stage_coef = ph[p].sc;
            A.mode = ph[p].mode;
            k_stage<<<GROUPS * 8, 256, 0, stream>>>(A);
        }
    }
}

// Round 7
// 1689.722 us; speedup vs baseline: 1.7117x; 1.1028x over previous
//
#include <hip/hip_runtime.h>

#define NN 50000
#define NE 1600000
#define DIM 32
#define HS 0.1f
#define NBPS 782       // cdiv(NN, 64) blocks per sign

static inline int cdiv(int a, int b) { return (a + b - 1) / b; }

// bf16x4 (uint2) -> float4
__device__ __forceinline__ float4 bf4_to_f4(uint2 u) {
    float4 v;
    v.x = __uint_as_float(u.x << 16);
    v.y = __uint_as_float(u.x & 0xffff0000u);
    v.z = __uint_as_float(u.y << 16);
    v.w = __uint_as_float(u.y & 0xffff0000u);
    return v;
}
__device__ __forceinline__ unsigned pack_bf2(float a, float b) {
    unsigned ua = __float_as_uint(a);
    ua = (ua + 0x7fffu + ((ua >> 16) & 1u)) >> 16;
    unsigned ub = __float_as_uint(b);
    ub = (ub + 0x7fffu + ((ub >> 16) & 1u)) & 0xffff0000u;
    return ua | ub;
}

// ---------------- setup kernels ----------------

__global__ void k_zero_ints(int* __restrict__ p, int n) {
    int i = blockIdx.x * blockDim.x + threadIdx.x;
    if (i < n) p[i] = 0;
}

__global__ void k_hist(const int* __restrict__ dst, int* __restrict__ cnt) {
    int i = blockIdx.x * blockDim.x + threadIdx.x;
    if (i < NE) atomicAdd(&cnt[dst[i]], 1);
}

// prefix over PADDED degree (rounded up to 8) -> row_ptr
__global__ __launch_bounds__(1024) void k_scanA(const int* __restrict__ cnt,
                                                int* __restrict__ row_ptr,
                                                int* __restrict__ partials) {
    __shared__ int s[1024];
    int t = threadIdx.x;
    int g = blockIdx.x * 1024 + t;
    int v = (g < NN) ? ((cnt[g] + 7) & ~7) : 0;
    s[t] = v;
    __syncthreads();
    for (int off = 1; off < 1024; off <<= 1) {
        int add = (t >= off) ? s[t - off] : 0;
        __syncthreads();
        s[t] += add;
        __syncthreads();
    }
    if (g < NN) row_ptr[g + 1] = s[t];
    if (t == 1023) partials[blockIdx.x] = s[t];
}

__global__ void k_scanB(int* __restrict__ partials, int nb) {
    if (threadIdx.x == 0 && blockIdx.x == 0) {
        int run = 0;
        for (int i = 0; i < nb; i++) { int v = partials[i]; partials[i] = run; run += v; }
    }
}

__global__ void k_scanC(int* __restrict__ row_ptr, const int* __restrict__ partials) {
    int g = blockIdx.x * blockDim.x + threadIdx.x;
    if (g < NN) row_ptr[g + 1] += partials[g >> 10];
    if (g == 0) row_ptr[0] = 0;
}

__global__ void k_dis(const int* __restrict__ cnt, float* __restrict__ dis) {
    int n = blockIdx.x * blockDim.x + threadIdx.x;
    if (n < NN) dis[n] = rsqrtf((float)cnt[n] + 1.0f);  // +1 self-loop
}

// scatter edges; 4B record = (src << 15) | fix15(dis[s]*dis[d])
__global__ void k_fill(const int* __restrict__ src, const int* __restrict__ dst,
                       const int* __restrict__ row_ptr, const float* __restrict__ dis,
                       int* __restrict__ fill, unsigned* __restrict__ cw) {
    int i = blockIdx.x * blockDim.x + threadIdx.x;
    if (i < NE) {
        int s = src[i], d = dst[i];
        int slot = row_ptr[d] + atomicAdd(&fill[d], 1);
        float w = dis[s] * dis[d];   // in (0, 1]
        cw[slot] = ((unsigned)s << 15) | (unsigned)(w * 32767.f + 0.5f);
    }
}

// zero the pad slots (rec=0 -> src 0, weight 0: harmless gather of row 0)
__global__ void k_pad(const int* __restrict__ row_ptr, const int* __restrict__ cnt,
                      unsigned* __restrict__ cw) {
    int n = blockIdx.x * blockDim.x + threadIdx.x;
    if (n < NN) {
        int e = row_ptr[n] + cnt[n], e1 = row_ptr[n + 1];
        for (; e < e1; ++e) cw[e] = 0u;
    }
}

// ---------------- initial matmul (x @ W -> xw bf16, copy x -> x_cur) ----------------

__global__ __launch_bounds__(256) void k_matmul(const float* __restrict__ src,
                                                const float* __restrict__ W,
                                                uint2* __restrict__ xw,
                                                float* __restrict__ copy_out) {
    __shared__ float sW[DIM * DIM];
    __shared__ float sX[32 * 33];
    int t = threadIdx.x;
#pragma unroll
    for (int k = 0; k < 4; k++) { int i = k * 256 + t; sW[i] = W[i]; }
    size_t base = (size_t)blockIdx.x * 32 * DIM;
#pragma unroll
    for (int k = 0; k < 4; k++) {
        int i = k * 256 + t;
        size_t g = base + i;
        float v = 0.f;
        if (g < (size_t)NN * DIM) {
            v = src[g];
            copy_out[g] = v;
        }
        sX[(i >> 5) * 33 + (i & 31)] = v;
    }
    __syncthreads();
    int r = t >> 3, oct = t & 7;
    int row = blockIdx.x * 32 + r;
    if (row >= NN) return;
    float a0 = 0.f, a1 = 0.f, a2 = 0.f, a3 = 0.f;
    const float* xr = &sX[r * 33];
#pragma unroll
    for (int i = 0; i < DIM; i++) {
        float xv = xr[i];
        const float* wr = &sW[i * DIM + oct * 4];
        a0 = fmaf(xv, wr[0], a0);
        a1 = fmaf(xv, wr[1], a1);
        a2 = fmaf(xv, wr[2], a2);
        a3 = fmaf(xv, wr[3], a3);
    }
    xw[(size_t)row * 8 + oct] = make_uint2(pack_bf2(a0, a1), pack_bf2(a2, a3));
}

// ---------------- fused stage kernel ----------------
// 4 lanes/node, 16B (uint4 = 8 bf16 cols) per lane. 64 nodes / 256-thread block.
// Edge lists padded to multiple of 8 -> no tail loop. Rec loads software-
// pipelined one iteration ahead of the gathers they feed.

struct SignP {
    const int* row_ptr; const unsigned* cw; const float* dis;
    const uint4* xw_in; uint4* xw_out;
    float* acc; float* x_cur;
    const float* W; const float* b; const float* wt;
    float* zout;
};
struct StageArgs { SignP s[2]; float t, acc_coef, stage_coef; int mode; };

#define EDGE_FMA(r, u)                                              \
    {                                                               \
        float wE = (float)((r) & 32767u) * (1.f / 32767.f);         \
        float4 vA = bf4_to_f4(make_uint2((u).x, (u).y));            \
        float4 vB = bf4_to_f4(make_uint2((u).z, (u).w));            \
        sum0.x = fmaf(wE, vA.x, sum0.x);                            \
        sum0.y = fmaf(wE, vA.y, sum0.y);                            \
        sum0.z = fmaf(wE, vA.z, sum0.z);                            \
        sum0.w = fmaf(wE, vA.w, sum0.w);                            \
        sum1.x = fmaf(wE, vB.x, sum1.x);                            \
        sum1.y = fmaf(wE, vB.y, sum1.y);                            \
        sum1.z = fmaf(wE, vB.z, sum1.z);                            \
        sum1.w = fmaf(wE, vB.w, sum1.w);                            \
    }

__global__ __launch_bounds__(256) void k_stage(StageArgs A) {
    int sg = blockIdx.x & 1;
    int blk = blockIdx.x >> 1;
    SignP P = A.s[sg];

    __shared__ float sW[DIM * DIM];   // 4 KB
    __shared__ float sR[64 * 36];     // 9 KB; stride 36 floats (16B-aligned rows)
    int tid = threadIdx.x;
    if (A.mode != 5) {
#pragma unroll
        for (int k = 0; k < 4; k++) { int i = k * 256 + tid; sW[i] = P.W[i]; }
    }

    int c = tid & 3;              // column octet: cols c*8 .. c*8+7
    int nl = tid >> 2;            // local node 0..63
    int n = blk * 64 + nl;
    bool active = n < NN;
    float4 r40 = make_float4(0.f, 0.f, 0.f, 0.f);
    float4 r41 = make_float4(0.f, 0.f, 0.f, 0.f);

    if (active) {
        int e = P.row_ptr[n], e1 = P.row_ptr[n + 1];   // (e1-e) % 8 == 0
        const uint4* xwq = P.xw_in + c;   // row stride = 4 uint4 (64 B)
        float4 sum0 = make_float4(0.f, 0.f, 0.f, 0.f);
        float4 sum1 = make_float4(0.f, 0.f, 0.f, 0.f);
        unsigned r0, r1, r2, r3, r4, r5, r6, r7;
        if (e < e1) {
            r0 = P.cw[e];     r1 = P.cw[e + 1]; r2 = P.cw[e + 2]; r3 = P.cw[e + 3];
            r4 = P.cw[e + 4]; r5 = P.cw[e + 5]; r6 = P.cw[e + 6]; r7 = P.cw[e + 7];
        }
        while (e < e1) {
            uint4 u0 = xwq[(size_t)(r0 >> 15) * 4];
            uint4 u1 = xwq[(size_t)(r1 >> 15) * 4];
            uint4 u2 = xwq[(size_t)(r2 >> 15) * 4];
            uint4 u3 = xwq[(size_t)(r3 >> 15) * 4];
            uint4 u4 = xwq[(size_t)(r4 >> 15) * 4];
            uint4 u5 = xwq[(size_t)(r5 >> 15) * 4];
            uint4 u6 = xwq[(size_t)(r6 >> 15) * 4];
            uint4 u7 = xwq[(size_t)(r7 >> 15) * 4];
            int en = e + 8;
            unsigned t0, t1, t2, t3, t4, t5, t6, t7;
            if (en < e1) {   // prefetch next recs while gathers are in flight
                t0 = P.cw[en];     t1 = P.cw[en + 1]; t2 = P.cw[en + 2]; t3 = P.cw[en + 3];
                t4 = P.cw[en + 4]; t5 = P.cw[en + 5]; t6 = P.cw[en + 6]; t7 = P.cw[en + 7];
            }
            EDGE_FMA(r0, u0) EDGE_FMA(r1, u1) EDGE_FMA(r2, u2) EDGE_FMA(r3, u3)
            EDGE_FMA(r4, u4) EDGE_FMA(r5, u5) EDGE_FMA(r6, u6) EDGE_FMA(r7, u7)
            if (en < e1) {
                r0 = t0; r1 = t1; r2 = t2; r3 = t3;
                r4 = t4; r5 = t5; r6 = t6; r7 = t7;
            }
            e = en;
        }
        float dn = P.dis[n];
        float sn = dn * dn;
        uint4 un = xwq[(size_t)n * 4];
        float4 vn0 = bf4_to_f4(make_uint2(un.x, un.y));
        float4 vn1 = bf4_to_f4(make_uint2(un.z, un.w));
        float4 bb0 = *(const float4*)&P.b[c * 8];
        float4 bb1 = *(const float4*)&P.b[c * 8 + 4];
        sum0.x = fmaf(sn, vn0.x, sum0.x) + bb0.x;
        sum0.y = fmaf(sn, vn0.y, sum0.y) + bb0.y;
        sum0.z = fmaf(sn, vn0.z, sum0.z) + bb0.z;
        sum0.w = fmaf(sn, vn0.w, sum0.w) + bb0.w;
        sum1.x = fmaf(sn, vn1.x, sum1.x) + bb1.x;
        sum1.y = fmaf(sn, vn1.y, sum1.y) + bb1.y;
        sum1.z = fmaf(sn, vn1.z, sum1.z) + bb1.z;
        sum1.w = fmaf(sn, vn1.w, sum1.w) + bb1.w;
        float4 w40 = *(const float4*)&P.wt[c * 8];
        float4 w41 = *(const float4*)&P.wt[c * 8 + 4];
        float t = A.t;
        float4 kv0, kv1;
        kv0.x = fmaxf(sum0.x, 0.f) / (1.f + __expf(-t * w40.x));
        kv0.y = fmaxf(sum0.y, 0.f) / (1.f + __expf(-t * w40.y));
        kv0.z = fmaxf(sum0.z, 0.f) / (1.f + __expf(-t * w40.z));
        kv0.w = fmaxf(sum0.w, 0.f) / (1.f + __expf(-t * w40.w));
        kv1.x = fmaxf(sum1.x, 0.f) / (1.f + __expf(-t * w41.x));
        kv1.y = fmaxf(sum1.y, 0.f) / (1.f + __expf(-t * w41.y));
        kv1.z = fmaxf(sum1.z, 0.f) / (1.f + __expf(-t * w41.z));
        kv1.w = fmaxf(sum1.w, 0.f) / (1.f + __expf(-t * w41.w));

        size_t o = (size_t)n * DIM + c * 8;
        float4 xc0 = *(const float4*)&P.x_cur[o];
        float4 xc1 = *(const float4*)&P.x_cur[o + 4];
        if (A.mode == 1) {
            *(float4*)&P.acc[o] = kv0;
            *(float4*)&P.acc[o + 4] = kv1;
            float sc = A.stage_coef;
            r40.x = fmaf(sc, kv0.x, xc0.x); r40.y = fmaf(sc, kv0.y, xc0.y);
            r40.z = fmaf(sc, kv0.z, xc0.z); r40.w = fmaf(sc, kv0.w, xc0.w);
            r41.x = fmaf(sc, kv1.x, xc1.x); r41.y = fmaf(sc, kv1.y, xc1.y);
            r41.z = fmaf(sc, kv1.z, xc1.z); r41.w = fmaf(sc, kv1.w, xc1.w);
        } else if (A.mode <= 3) {
            float4 ap0 = *(const float4*)&P.acc[o];
            float4 ap1 = *(const float4*)&P.acc[o + 4];
            float ac = A.acc_coef, sc = A.stage_coef;
            float4 a0, a1;
            a0.x = fmaf(ac, kv0.x, ap0.x); a0.y = fmaf(ac, kv0.y, ap0.y);
            a0.z = fmaf(ac, kv0.z, ap0.z); a0.w = fmaf(ac, kv0.w, ap0.w);
            a1.x = fmaf(ac, kv1.x, ap1.x); a1.y = fmaf(ac, kv1.y, ap1.y);
            a1.z = fmaf(ac, kv1.z, ap1.z); a1.w = fmaf(ac, kv1.w, ap1.w);
            *(float4*)&P.acc[o] = a0;
            *(float4*)&P.acc[o + 4] = a1;
            r40.x = fmaf(sc, kv0.x, xc0.x); r40.y = fmaf(sc, kv0.y, xc0.y);
            r40.z = fmaf(sc, kv0.z, xc0.z); r40.w = fmaf(sc, kv0.w, xc0.w);
            r41.x = fmaf(sc, kv1.x, xc1.x); r41.y = fmaf(sc, kv1.y, xc1.y);
            r41.z = fmaf(sc, kv1.z, xc1.z); r41.w = fmaf(sc, kv1.w, xc1.w);
        } else {
            float4 ap0 = *(const float4*)&P.acc[o];
            float4 ap1 = *(const float4*)&P.acc[o + 4];
            float4 a0, a1;
            a0.x = ap0.x + kv0.x; a0.y = ap0.y + kv0.y;
            a0.z = ap0.z + kv0.z; a0.w = ap0.w + kv0.w;
            a1.x = ap1.x + kv1.x; a1.y = ap1.y + kv1.y;
            a1.z = ap1.z + kv1.z; a1.w = ap1.w + kv1.w;
            r40.x = fmaf(HS / 6.f, a0.x, xc0.x); r40.y = fmaf(HS / 6.f, a0.y, xc0.y);
            r40.z = fmaf(HS / 6.f, a0.z, xc0.z); r40.w = fmaf(HS / 6.f, a0.w, xc0.w);
            r41.x = fmaf(HS / 6.f, a1.x, xc1.x); r41.y = fmaf(HS / 6.f, a1.y, xc1.y);
            r41.z = fmaf(HS / 6.f, a1.z, xc1.z); r41.w = fmaf(HS / 6.f, a1.w, xc1.w);
            if (A.mode == 4) {
                *(float4*)&P.x_cur[o] = r40;
                *(float4*)&P.x_cur[o + 4] = r41;
            } else {
                *(float4*)&P.zout[o] = r40;
                *(float4*)&P.zout[o + 4] = r41;
            }
        }
    }

    if (A.mode == 5) return;  // uniform; no thread reaches the barrier

    // epilogue matmul: xw_out[n] = r4-row @ W, stored bf16
    *(float4*)&sR[nl * 36 + c * 8] = r40;
    *(float4*)&sR[nl * 36 + c * 8 + 4] = r41;
    __syncthreads();
    if (active) {
        float4 y0 = make_float4(0.f, 0.f, 0.f, 0.f);
        float4 y1 = make_float4(0.f, 0.f, 0.f, 0.f);
        const float* row = &sR[nl * 36];
#pragma unroll
        for (int i = 0; i < DIM; i++) {
            float sv = row[i];
            float4 wA = *(const float4*)&sW[i * DIM + c * 8];
            float4 wB = *(const float4*)&sW[i * DIM + c * 8 + 4];
            y0.x = fmaf(sv, wA.x, y0.x); y0.y = fmaf(sv, wA.y, y0.y);
            y0.z = fmaf(sv, wA.z, y0.z); y0.w = fmaf(sv, wA.w, y0.w);
            y1.x = fmaf(sv, wB.x, y1.x); y1.y = fmaf(sv, wB.y, y1.y);
            y1.z = fmaf(sv, wB.z, y1.z); y1.w = fmaf(sv, wB.w, y1.w);
        }
        P.xw_out[(size_t)n * 4 + c] =
            make_uint4(pack_bf2(y0.x, y0.y), pack_bf2(y0.z, y0.w),
                       pack_bf2(y1.x, y1.y), pack_bf2(y1.z, y1.w));
    }
}

// ---------------- host ----------------

extern "C" void kernel_launch(void* const* d_in, const int* in_sizes, int n_in,
                              void* d_out, int out_size, void* d_ws, size_t ws_size,
                              hipStream_t stream) {
    const float* x   = (const float*)d_in[0];
    const int* epos  = (const int*)d_in[1];
    const int* eneg  = (const int*)d_in[2];
    const float* Wp  = (const float*)d_in[3];
    const float* bp  = (const float*)d_in[4];
    const float* wtp = (const float*)d_in[5];
    const float* Wn  = (const float*)d_in[6];
    const float* bn  = (const float*)d_in[7];
    const float* wtn = (const float*)d_in[8];
    float* out = (float*)d_out;

    char* ws = (char*)d_ws;
    size_t off = 0;
    auto alloc = [&](size_t bytes) -> void* {
        void* p = ws + off;
        off += (bytes + 255) & ~(size_t)255;
        return p;
    };

    struct Sign {
        int *row_ptr, *cnt, *fill, *partials;
        float* dis;
        unsigned* cw;
        float *x_cur, *acc;
        uint4* xwbuf[2];
        const int *src, *dst;
        const float *W, *b, *wt;
        float* zout;
    } S[2];

    const size_t CWCAP = (size_t)NE + 8u * NN;  // padded capacity

    for (int s = 0; s < 2; s++) {
        S[s].row_ptr  = (int*)alloc((NN + 1) * sizeof(int));
        int* cntfill  = (int*)alloc((size_t)2 * NN * sizeof(int));
        S[s].cnt = cntfill;
        S[s].fill = cntfill + NN;
        S[s].partials = (int*)alloc(256);
        S[s].dis      = (float*)alloc(NN * sizeof(float));
        S[s].cw       = (unsigned*)alloc(CWCAP * sizeof(unsigned));
        S[s].x_cur    = (float*)alloc((size_t)NN * DIM * sizeof(float));
        S[s].acc      = (float*)alloc((size_t)NN * DIM * sizeof(float));
        S[s].xwbuf[0] = (uint4*)alloc((size_t)NN * DIM * 2);
        S[s].xwbuf[1] = (uint4*)alloc((size_t)NN * DIM * 2);
    }
    S[0].src = epos; S[0].dst = epos + NE; S[0].W = Wp; S[0].b = bp; S[0].wt = wtp;
    S[0].zout = out;
    S[1].src = eneg; S[1].dst = eneg + NE; S[1].W = Wn; S[1].b = bn; S[1].wt = wtn;
    S[1].zout = out + (size_t)NN * DIM;

    const int nbScan = cdiv(NN, 1024);

    // ---- setup: build padded CSR + norms for both signs ----
    for (int s = 0; s < 2; s++) {
        k_zero_ints<<<cdiv(2 * NN, 256), 256, 0, stream>>>(S[s].cnt, 2 * NN);
        k_hist<<<cdiv(NE, 256), 256, 0, stream>>>(S[s].dst, S[s].cnt);
        k_scanA<<<nbScan, 1024, 0, stream>>>(S[s].cnt, S[s].row_ptr, S[s].partials);
        k_scanB<<<1, 1, 0, stream>>>(S[s].partials, nbScan);
        k_scanC<<<cdiv(NN, 256), 256, 0, stream>>>(S[s].row_ptr, S[s].partials);
        k_dis<<<cdiv(NN, 256), 256, 0, stream>>>(S[s].cnt, S[s].dis);
        k_fill<<<cdiv(NE, 256), 256, 0, stream>>>(S[s].src, S[s].dst, S[s].row_ptr,
                                                  S[s].dis, S[s].fill, S[s].cw);
        k_pad<<<cdiv(NN, 256), 256, 0, stream>>>(S[s].row_ptr, S[s].cnt, S[s].cw);
    }

    // initial xw = bf16(x @ W), x_cur = x
    for (int s = 0; s < 2; s++)
        k_matmul<<<cdiv(NN, 32), 256, 0, stream>>>(x, S[s].W, (uint2*)S[s].xwbuf[0],
                                                   S[s].x_cur);

    // ---- RK4 main loop: 4 fused stages per step, both signs per dispatch ----
    for (int st = 0; st < 10; st++) {
        float tb = HS * (float)st;
        struct Ph { float t, ac, sc; int mode, in, out; } ph[4] = {
            { tb,             1.f, HS * 0.5f, 1,              0, 1 },
            { tb + HS * 0.5f, 2.f, HS * 0.5f, 2,              1, 0 },
            { tb + HS * 0.5f, 2.f, HS,        3,              0, 1 },
            { tb + HS,        1.f, 0.f,       st == 9 ? 5 : 4, 1, 0 },
        };
        for (int p = 0; p < 4; p++) {
            StageArgs A;
            for (int s = 0; s < 2; s++) {
                A.s[s].row_ptr = S[s].row_ptr;
                A.s[s].cw      = S[s].cw;
                A.s[s].dis     = S[s].dis;
                A.s[s].xw_in   = S[s].xwbuf[ph[p].in];
                A.s[s].xw_out  = S[s].xwbuf[ph[p].out];
                A.s[s].acc     = S[s].acc;
                A.s[s].x_cur   = S[s].x_cur;
                A.s[s].W       = S[s].W;
                A.s[s].b       = S[s].b;
                A.s[s].wt      = S[s].wt;
                A.s[s].zout    = S[s].zout;
            }
            A.t = ph[p].t; A.acc_coef = ph[p].ac; A.stage_coef = ph[p].sc;
            A.mode = ph[p].mode;
            k_stage<<<2 * NBPS, 256, 0, stream>>>(A);
        }
    }
}